// Round 1
// baseline (1612.650 us; speedup 1.0000x reference)
//
#include <hip/hip_runtime.h>
#include <stdint.h>

typedef __bf16 bf16_t;
typedef __bf16 bf16x8 __attribute__((ext_vector_type(8)));
typedef float  f32x4  __attribute__((ext_vector_type(4)));

#define M_DIM 32768
#define N_DIM 4096
#define K_DIM 4096
#define BM 128
#define BN 128
#define BK 32
#define NK (K_DIM / BK)

typedef const __attribute__((address_space(1))) void gvoid;
typedef __attribute__((address_space(3))) void lvoid;

// ---------------- fp32 -> bf16 conversion (vectorized, grid-stride) ----------
__global__ void cvt_f32_bf16(const float* __restrict__ in, bf16_t* __restrict__ out,
                             long long n) {
  long long i = ((long long)blockIdx.x * blockDim.x + threadIdx.x) * 8;
  long long stride = (long long)gridDim.x * blockDim.x * 8;
  for (; i < n; i += stride) {
    float4 a = *(const float4*)(in + i);
    float4 b = *(const float4*)(in + i + 4);
    bf16x8 o;
    o[0] = (bf16_t)a.x; o[1] = (bf16_t)a.y; o[2] = (bf16_t)a.z; o[3] = (bf16_t)a.w;
    o[4] = (bf16_t)b.x; o[5] = (bf16_t)b.y; o[6] = (bf16_t)b.z; o[7] = (bf16_t)b.w;
    *(bf16x8*)(out + i) = o;
  }
}

__device__ inline bf16x8 cvt8(float4 a, float4 b) {
  bf16x8 o;
  o[0] = (bf16_t)a.x; o[1] = (bf16_t)a.y; o[2] = (bf16_t)a.z; o[3] = (bf16_t)a.w;
  o[4] = (bf16_t)b.x; o[5] = (bf16_t)b.y; o[6] = (bf16_t)b.z; o[7] = (bf16_t)b.w;
  return o;
}

// ---------------- GEMM: C[M][N] = A[M][K] * B[N][K]^T + bias ----------------
// PATH 0: A,B already bf16 (preconverted in ws), stage via global_load_lds x16
// PATH 1: A,B fp32; reg-stage (global->VGPR->cvt->ds_write_b128)
template <int PATH>
__global__ __launch_bounds__(256, 2)
void gemm_bt(const void* __restrict__ Ap, const void* __restrict__ Bp,
             const float* __restrict__ bias, float* __restrict__ out) {
  __shared__ bf16_t As[2][BM * BK];
  __shared__ bf16_t Bs[2][BN * BK];

  const int nwg_n = N_DIM / BN;                 // 32
  const int nwg = (M_DIM / BM) * nwg_n;         // 8192 (divisible by 8)
  int bid = blockIdx.x;
  int swz = (bid & 7) * (nwg >> 3) + (bid >> 3);  // XCD-aware, bijective
  const int bm0 = (swz / nwg_n) * BM;
  const int bn0 = (swz % nwg_n) * BN;

  const int tid = threadIdx.x;
  const int lane = tid & 63;
  const int wave = tid >> 6;
  const int wr = wave >> 1;   // 2x2 wave grid, 64x64 out per wave
  const int wc = wave & 1;

  // staging map: thread t covers tile bytes [t*16, t*16+16); chunk s=1 adds 4096B (64 rows)
  const int arow = tid >> 2;            // 0..63
  const int ae = (tid & 3) * 8;         // element offset within row
  const int ldsoff = tid * 8;           // element offset into LDS tile

  f32x4 acc[4][4];
#pragma unroll
  for (int i = 0; i < 4; ++i)
#pragma unroll
    for (int j = 0; j < 4; ++j) acc[i][j] = (f32x4){0.f, 0.f, 0.f, 0.f};

  // LDS fragment read offsets (A row / B row = output col), 16B-aligned
  int aoff[4], boff[4];
#pragma unroll
  for (int i = 0; i < 4; ++i) {
    aoff[i] = (wr * 64 + i * 16 + (lane & 15)) * BK + (lane >> 4) * 8;
    boff[i] = (wc * 64 + i * 16 + (lane & 15)) * BK + (lane >> 4) * 8;
  }

  if constexpr (PATH == 0) {
    const bf16_t* gA = (const bf16_t*)Ap + (long long)(bm0 + arow) * K_DIM + ae;
    const bf16_t* gB = (const bf16_t*)Bp + (long long)(bn0 + arow) * K_DIM + ae;

    auto stage = [&](int buf, int kt) {
      __builtin_amdgcn_global_load_lds((gvoid*)(gA + kt), (lvoid*)&As[buf][ldsoff], 16, 0, 0);
      __builtin_amdgcn_global_load_lds((gvoid*)(gA + 64 * K_DIM + kt),
                                       (lvoid*)&As[buf][2048 + ldsoff], 16, 0, 0);
      __builtin_amdgcn_global_load_lds((gvoid*)(gB + kt), (lvoid*)&Bs[buf][ldsoff], 16, 0, 0);
      __builtin_amdgcn_global_load_lds((gvoid*)(gB + 64 * K_DIM + kt),
                                       (lvoid*)&Bs[buf][2048 + ldsoff], 16, 0, 0);
    };

    stage(0, 0);
    __syncthreads();
    int buf = 0;
    for (int t = 0; t < NK; ++t) {
      if (t + 1 < NK) stage(buf ^ 1, (t + 1) * BK);
      bf16x8 af[4], bfr[4];
#pragma unroll
      for (int i = 0; i < 4; ++i) af[i] = *(const bf16x8*)&As[buf][aoff[i]];
#pragma unroll
      for (int j = 0; j < 4; ++j) bfr[j] = *(const bf16x8*)&Bs[buf][boff[j]];
#pragma unroll
      for (int i = 0; i < 4; ++i)
#pragma unroll
        for (int j = 0; j < 4; ++j)
          acc[i][j] = __builtin_amdgcn_mfma_f32_16x16x32_bf16(af[i], bfr[j], acc[i][j], 0, 0, 0);
      __syncthreads();
      buf ^= 1;
    }
  } else {
    const float* gA = (const float*)Ap + (long long)(bm0 + arow) * K_DIM + ae;
    const float* gB = (const float*)Bp + (long long)(bn0 + arow) * K_DIM + ae;

    {  // prologue: stage tile 0
      float4 a0 = *(const float4*)(gA), a1 = *(const float4*)(gA + 4);
      float4 a2 = *(const float4*)(gA + 64 * K_DIM), a3 = *(const float4*)(gA + 64 * K_DIM + 4);
      float4 b0 = *(const float4*)(gB), b1 = *(const float4*)(gB + 4);
      float4 b2 = *(const float4*)(gB + 64 * K_DIM), b3 = *(const float4*)(gB + 64 * K_DIM + 4);
      *(bf16x8*)&As[0][ldsoff] = cvt8(a0, a1);
      *(bf16x8*)&As[0][2048 + ldsoff] = cvt8(a2, a3);
      *(bf16x8*)&Bs[0][ldsoff] = cvt8(b0, b1);
      *(bf16x8*)&Bs[0][2048 + ldsoff] = cvt8(b2, b3);
    }
    __syncthreads();
    int buf = 0;
    for (int t = 0; t < NK; ++t) {
      float4 a0, a1, a2, a3, b0, b1, b2, b3;
      const bool pf = (t + 1 < NK);
      if (pf) {  // issue next-tile loads early (latency hides under MFMA)
        int kt = (t + 1) * BK;
        a0 = *(const float4*)(gA + kt); a1 = *(const float4*)(gA + kt + 4);
        a2 = *(const float4*)(gA + 64 * K_DIM + kt); a3 = *(const float4*)(gA + 64 * K_DIM + kt + 4);
        b0 = *(const float4*)(gB + kt); b1 = *(const float4*)(gB + kt + 4);
        b2 = *(const float4*)(gB + 64 * K_DIM + kt); b3 = *(const float4*)(gB + 64 * K_DIM + kt + 4);
      }
      bf16x8 af[4], bfr[4];
#pragma unroll
      for (int i = 0; i < 4; ++i) af[i] = *(const bf16x8*)&As[buf][aoff[i]];
#pragma unroll
      for (int j = 0; j < 4; ++j) bfr[j] = *(const bf16x8*)&Bs[buf][boff[j]];
#pragma unroll
      for (int i = 0; i < 4; ++i)
#pragma unroll
        for (int j = 0; j < 4; ++j)
          acc[i][j] = __builtin_amdgcn_mfma_f32_16x16x32_bf16(af[i], bfr[j], acc[i][j], 0, 0, 0);
      if (pf) {
        *(bf16x8*)&As[buf ^ 1][ldsoff] = cvt8(a0, a1);
        *(bf16x8*)&As[buf ^ 1][2048 + ldsoff] = cvt8(a2, a3);
        *(bf16x8*)&Bs[buf ^ 1][ldsoff] = cvt8(b0, b1);
        *(bf16x8*)&Bs[buf ^ 1][2048 + ldsoff] = cvt8(b2, b3);
      }
      __syncthreads();
      buf ^= 1;
    }
  }

  // epilogue: C/D layout col=lane&15, row=(lane>>4)*4+r  (guide §3, m89-verified)
#pragma unroll
  for (int j = 0; j < 4; ++j) {
    const int col = bn0 + wc * 64 + j * 16 + (lane & 15);
    const float bb = bias[col];
#pragma unroll
    for (int i = 0; i < 4; ++i) {
      const int row0 = bm0 + wr * 64 + i * 16 + (lane >> 4) * 4;
      f32x4 v = acc[i][j];
#pragma unroll
      for (int r = 0; r < 4; ++r)
        out[(long long)(row0 + r) * N_DIM + col] = v[r] + bb;
    }
  }
}

extern "C" void kernel_launch(void* const* d_in, const int* in_sizes, int n_in,
                              void* d_out, int out_size, void* d_ws, size_t ws_size,
                              hipStream_t stream) {
  const float* x = (const float*)d_in[0];     // [8,4096,4096] fp32
  const float* w = (const float*)d_in[1];     // [4096,4096] fp32, values {0,1,3}
  const float* bias = (const float*)d_in[2];  // [4096] fp32
  float* out = (float*)d_out;

  const size_t needA = (size_t)M_DIM * K_DIM * sizeof(bf16_t);  // 256 MiB
  const size_t needB = (size_t)N_DIM * K_DIM * sizeof(bf16_t);  // 32 MiB
  const int nblocks = (M_DIM / BM) * (N_DIM / BN);              // 8192

  if (ws_size >= needA + needB) {
    bf16_t* Ab = (bf16_t*)d_ws;
    bf16_t* Wb = (bf16_t*)((char*)d_ws + needA);
    cvt_f32_bf16<<<2048, 256, 0, stream>>>(x, Ab, (long long)M_DIM * K_DIM);
    cvt_f32_bf16<<<1024, 256, 0, stream>>>(w, Wb, (long long)N_DIM * K_DIM);
    gemm_bt<0><<<nblocks, 256, 0, stream>>>(Ab, Wb, bias, out);
  } else {
    gemm_bt<1><<<nblocks, 256, 0, stream>>>(x, w, bias, out);
  }
}

// Round 2
// 1214.693 us; speedup vs baseline: 1.3276x; 1.3276x over previous
//
#include <hip/hip_runtime.h>
#include <stdint.h>

typedef __bf16 bf16_t;
typedef __bf16 bf16x8 __attribute__((ext_vector_type(8)));
typedef float  f32x4  __attribute__((ext_vector_type(4)));

#define M_DIM 32768
#define N_DIM 4096
#define K_DIM 4096

// deep-pipeline GEMM geometry
#define BM 256
#define BN 256
#define BK 32
#define NT (K_DIM / BK)        // 128 K-steps
#define A_BYTES 16384          // 256 rows x 64 B
#define B_BYTES 16384          // 256 rows x 64 B
#define SLOT_BYTES (A_BYTES + B_BYTES)  // 32 KiB
#define NSLOT 4                // 128 KiB LDS ring

typedef const __attribute__((address_space(1))) void gvoid;
typedef __attribute__((address_space(3))) void lvoid;

// ---------------- fp32 -> bf16 conversion (vectorized, grid-stride) ----------
__global__ void cvt_f32_bf16(const float* __restrict__ in, bf16_t* __restrict__ out,
                             long long n) {
  long long i = ((long long)blockIdx.x * blockDim.x + threadIdx.x) * 8;
  long long stride = (long long)gridDim.x * blockDim.x * 8;
  for (; i < n; i += stride) {
    float4 a = *(const float4*)(in + i);
    float4 b = *(const float4*)(in + i + 4);
    bf16x8 o;
    o[0] = (bf16_t)a.x; o[1] = (bf16_t)a.y; o[2] = (bf16_t)a.z; o[3] = (bf16_t)a.w;
    o[4] = (bf16_t)b.x; o[5] = (bf16_t)b.y; o[6] = (bf16_t)b.z; o[7] = (bf16_t)b.w;
    *(bf16x8*)(out + i) = o;
  }
}

// ---------------- deep-pipelined GEMM: C = A[M][K] * W[N][K]^T + bias --------
// 8 waves (2M x 4N), per-wave 128x64 output. 4-slot LDS ring, stage 3 ahead,
// counted vmcnt(8), one barrier per K-step, XOR-swizzled LDS (linear dest +
// inverse-swizzled global source + swizzled ds_read).
__global__ __launch_bounds__(512, 2)
void gemm_deep(const bf16_t* __restrict__ A, const bf16_t* __restrict__ W,
               const float* __restrict__ bias, float* __restrict__ out) {
  __shared__ __align__(1024) char smem[NSLOT * SLOT_BYTES];  // 128 KiB

  const int nwg_n = N_DIM / BN;                 // 16
  const int nwg = (M_DIM / BM) * nwg_n;         // 2048 (divisible by 8)
  const int bid = blockIdx.x;
  const int swz = (bid & 7) * (nwg >> 3) + (bid >> 3);  // XCD-bijective
  const int bm0 = (swz / nwg_n) * BM;
  const int bn0 = (swz % nwg_n) * BN;

  const int tid = threadIdx.x;
  const int lane = tid & 63;
  const int wave = tid >> 6;
  const int wr = wave >> 2;   // 0..1 -> 128-row band
  const int wc = wave & 3;    // 0..3 -> 64-col band

  // ---- staging maps: per thread 2 A-chunks + 2 B-chunks of 16 B ----
  // LDS linear L = tid*16 + s*8192 ; logical row = L>>6 ;
  // logical col-byte c = (L&63) ^ ((row&3)<<4)   (inverse of read swizzle)
  const char* gA[2]; const char* gB[2]; int ldsA[2], ldsB[2];
#pragma unroll
  for (int s = 0; s < 2; ++s) {
    const int L = tid * 16 + s * 8192;
    const int row = L >> 6;
    const int c = (L & 63) ^ ((row & 3) << 4);
    gA[s] = (const char*)A + (long long)(bm0 + row) * (K_DIM * 2) + c;
    gB[s] = (const char*)W + (long long)(bn0 + row) * (K_DIM * 2) + c;
    ldsA[s] = L;
    ldsB[s] = A_BYTES + L;
  }

  auto stage = [&](int t) {
    const int slot = (t & 3) * SLOT_BYTES;
    const long long ko = (long long)t * (BK * 2);
#pragma unroll
    for (int s = 0; s < 2; ++s)
      __builtin_amdgcn_global_load_lds((gvoid*)(gA[s] + ko),
                                       (lvoid*)(smem + slot + ldsA[s]), 16, 0, 0);
#pragma unroll
    for (int s = 0; s < 2; ++s)
      __builtin_amdgcn_global_load_lds((gvoid*)(gB[s] + ko),
                                       (lvoid*)(smem + slot + ldsB[s]), 16, 0, 0);
  };

  // issue 3 K-steps of staging up front (12 loads in flight per wave)
  stage(0); stage(1); stage(2);

  // ---- fragment LDS byte offsets (swizzled), iteration-invariant ----
  int aoff[8], boff[4];
#pragma unroll
  for (int i = 0; i < 8; ++i) {
    const int r = wr * 128 + i * 16 + (lane & 15);
    aoff[i] = r * 64 + ((((lane >> 4) << 4)) ^ ((r & 3) << 4));
  }
#pragma unroll
  for (int j = 0; j < 4; ++j) {
    const int r = wc * 64 + j * 16 + (lane & 15);
    boff[j] = A_BYTES + r * 64 + ((((lane >> 4) << 4)) ^ ((r & 3) << 4));
  }

  f32x4 acc[8][4];
#pragma unroll
  for (int i = 0; i < 8; ++i)
#pragma unroll
    for (int j = 0; j < 4; ++j) acc[i][j] = (f32x4){0.f, 0.f, 0.f, 0.f};

  for (int t = 0; t < NT; ++t) {
    // tile t fully landed for every wave after [own vmcnt ; barrier]
    if (t < NT - 2)       asm volatile("s_waitcnt vmcnt(8)" ::: "memory");
    else if (t == NT - 2) asm volatile("s_waitcnt vmcnt(4)" ::: "memory");
    else                  asm volatile("s_waitcnt vmcnt(0)" ::: "memory");
    __builtin_amdgcn_s_barrier();
    __builtin_amdgcn_sched_barrier(0);

    // prefetch K-step t+3 into slot (t+3)&3 (= slot of t-1, consumed: all
    // waves passed the barrier only after their lgkmcnt(0) drain at t-1)
    if (t < NT - 3) stage(t + 3);

    const char* base = smem + (t & 3) * SLOT_BYTES;
    bf16x8 af[8], bfr[4];
#pragma unroll
    for (int i = 0; i < 8; ++i) af[i] = *(const bf16x8*)(base + aoff[i]);
#pragma unroll
    for (int j = 0; j < 4; ++j) bfr[j] = *(const bf16x8*)(base + boff[j]);

    // all ds_reads complete before this wave can reach the next barrier
    asm volatile("s_waitcnt lgkmcnt(0)" ::: "memory");
    __builtin_amdgcn_sched_barrier(0);

    __builtin_amdgcn_s_setprio(1);
#pragma unroll
    for (int i = 0; i < 8; ++i)
#pragma unroll
      for (int j = 0; j < 4; ++j)
        acc[i][j] = __builtin_amdgcn_mfma_f32_16x16x32_bf16(af[i], bfr[j], acc[i][j], 0, 0, 0);
    __builtin_amdgcn_s_setprio(0);
  }

  // epilogue: C/D layout col=lane&15, row=(lane>>4)*4+r (m89-verified)
#pragma unroll
  for (int j = 0; j < 4; ++j) {
    const int col = bn0 + wc * 64 + j * 16 + (lane & 15);
    const float bb = bias[col];
#pragma unroll
    for (int i = 0; i < 8; ++i) {
      const int row0 = bm0 + wr * 128 + i * 16 + (lane >> 4) * 4;
      f32x4 v = acc[i][j];
#pragma unroll
      for (int r = 0; r < 4; ++r)
        out[(long long)(row0 + r) * N_DIM + col] = v[r] + bb;
    }
  }
}

// ---------------- fallback (ws too small): fp32 reg-staged 128^2 ------------
__global__ __launch_bounds__(256, 2)
void gemm_small(const float* __restrict__ Ap, const float* __restrict__ Bp,
                const float* __restrict__ bias, float* __restrict__ out) {
  __shared__ bf16_t As[2][128 * 32];
  __shared__ bf16_t Bs[2][128 * 32];
  const int nwg_n = N_DIM / 128;
  const int nwg = (M_DIM / 128) * nwg_n;
  int bid = blockIdx.x;
  int swz = (bid & 7) * (nwg >> 3) + (bid >> 3);
  const int bm0 = (swz / nwg_n) * 128;
  const int bn0 = (swz % nwg_n) * 128;
  const int tid = threadIdx.x;
  const int lane = tid & 63;
  const int wave = tid >> 6;
  const int wr = wave >> 1, wc = wave & 1;
  const int arow = tid >> 2, ae = (tid & 3) * 8, ldsoff = tid * 8;
  f32x4 acc[4][4];
#pragma unroll
  for (int i = 0; i < 4; ++i)
#pragma unroll
    for (int j = 0; j < 4; ++j) acc[i][j] = (f32x4){0.f, 0.f, 0.f, 0.f};
  int aoff[4], boff[4];
#pragma unroll
  for (int i = 0; i < 4; ++i) {
    aoff[i] = (wr * 64 + i * 16 + (lane & 15)) * 32 + (lane >> 4) * 8;
    boff[i] = (wc * 64 + i * 16 + (lane & 15)) * 32 + (lane >> 4) * 8;
  }
  const float* gA = Ap + (long long)(bm0 + arow) * K_DIM + ae;
  const float* gB = Bp + (long long)(bn0 + arow) * K_DIM + ae;
  auto cvt8 = [](float4 a, float4 b) {
    bf16x8 o;
    o[0] = (bf16_t)a.x; o[1] = (bf16_t)a.y; o[2] = (bf16_t)a.z; o[3] = (bf16_t)a.w;
    o[4] = (bf16_t)b.x; o[5] = (bf16_t)b.y; o[6] = (bf16_t)b.z; o[7] = (bf16_t)b.w;
    return o;
  };
  {
    float4 a0 = *(const float4*)(gA), a1 = *(const float4*)(gA + 4);
    float4 a2 = *(const float4*)(gA + 64 * K_DIM), a3 = *(const float4*)(gA + 64 * K_DIM + 4);
    float4 b0 = *(const float4*)(gB), b1 = *(const float4*)(gB + 4);
    float4 b2 = *(const float4*)(gB + 64 * K_DIM), b3 = *(const float4*)(gB + 64 * K_DIM + 4);
    *(bf16x8*)&As[0][ldsoff] = cvt8(a0, a1);
    *(bf16x8*)&As[0][2048 + ldsoff] = cvt8(a2, a3);
    *(bf16x8*)&Bs[0][ldsoff] = cvt8(b0, b1);
    *(bf16x8*)&Bs[0][2048 + ldsoff] = cvt8(b2, b3);
  }
  __syncthreads();
  int buf = 0;
  for (int t = 0; t < K_DIM / 32; ++t) {
    float4 a0, a1, a2, a3, b0, b1, b2, b3;
    const bool pf = (t + 1 < K_DIM / 32);
    if (pf) {
      int kt = (t + 1) * 32;
      a0 = *(const float4*)(gA + kt); a1 = *(const float4*)(gA + kt + 4);
      a2 = *(const float4*)(gA + 64 * K_DIM + kt); a3 = *(const float4*)(gA + 64 * K_DIM + kt + 4);
      b0 = *(const float4*)(gB + kt); b1 = *(const float4*)(gB + kt + 4);
      b2 = *(const float4*)(gB + 64 * K_DIM + kt); b3 = *(const float4*)(gB + 64 * K_DIM + kt + 4);
    }
    bf16x8 af[4], bfr[4];
#pragma unroll
    for (int i = 0; i < 4; ++i) af[i] = *(const bf16x8*)&As[buf][aoff[i]];
#pragma unroll
    for (int j = 0; j < 4; ++j) bfr[j] = *(const bf16x8*)&Bs[buf][boff[j]];
#pragma unroll
    for (int i = 0; i < 4; ++i)
#pragma unroll
      for (int j = 0; j < 4; ++j)
        acc[i][j] = __builtin_amdgcn_mfma_f32_16x16x32_bf16(af[i], bfr[j], acc[i][j], 0, 0, 0);
    if (pf) {
      *(bf16x8*)&As[buf ^ 1][ldsoff] = cvt8(a0, a1);
      *(bf16x8*)&As[buf ^ 1][2048 + ldsoff] = cvt8(a2, a3);
      *(bf16x8*)&Bs[buf ^ 1][ldsoff] = cvt8(b0, b1);
      *(bf16x8*)&Bs[buf ^ 1][2048 + ldsoff] = cvt8(b2, b3);
    }
    __syncthreads();
    buf ^= 1;
  }
#pragma unroll
  for (int j = 0; j < 4; ++j) {
    const int col = bn0 + wc * 64 + j * 16 + (lane & 15);
    const float bb = bias[col];
#pragma unroll
    for (int i = 0; i < 4; ++i) {
      const int row0 = bm0 + wr * 64 + i * 16 + (lane >> 4) * 4;
      f32x4 v = acc[i][j];
#pragma unroll
      for (int r = 0; r < 4; ++r)
        out[(long long)(row0 + r) * N_DIM + col] = v[r] + bb;
    }
  }
}

extern "C" void kernel_launch(void* const* d_in, const int* in_sizes, int n_in,
                              void* d_out, int out_size, void* d_ws, size_t ws_size,
                              hipStream_t stream) {
  const float* x = (const float*)d_in[0];     // [8,4096,4096] fp32
  const float* w = (const float*)d_in[1];     // [4096,4096] fp32, {0,1,3}
  const float* bias = (const float*)d_in[2];  // [4096] fp32
  float* out = (float*)d_out;

  const size_t needA = (size_t)M_DIM * K_DIM * sizeof(bf16_t);  // 256 MiB
  const size_t needB = (size_t)N_DIM * K_DIM * sizeof(bf16_t);  // 32 MiB

  if (ws_size >= needA + needB) {
    bf16_t* Ab = (bf16_t*)d_ws;
    bf16_t* Wb = (bf16_t*)((char*)d_ws + needA);
    cvt_f32_bf16<<<2048, 256, 0, stream>>>(x, Ab, (long long)M_DIM * K_DIM);
    cvt_f32_bf16<<<1024, 256, 0, stream>>>(w, Wb, (long long)N_DIM * K_DIM);
    gemm_deep<<<(M_DIM / BM) * (N_DIM / BN), 512, 0, stream>>>(Ab, Wb, bias, out);
  } else {
    gemm_small<<<(M_DIM / 128) * (N_DIM / 128), 256, 0, stream>>>(x, w, bias, out);
  }
}

// Round 3
// 1171.677 us; speedup vs baseline: 1.3764x; 1.0367x over previous
//
#include <hip/hip_runtime.h>
#include <stdint.h>

typedef __bf16 bf16_t;
typedef __bf16 bf16x8 __attribute__((ext_vector_type(8)));
typedef float  f32x4  __attribute__((ext_vector_type(4)));

#define M_DIM 32768
#define N_DIM 4096
#define K_DIM 4096

// deep-pipeline GEMM geometry
#define BM 256
#define BN 256
#define BK 32
#define NT (K_DIM / BK)        // 128 K-steps
#define A_BYTES 16384          // 256 rows x 64 B
#define SLOT_BYTES 32768       // A half + B half
#define NSLOT 4                // 128 KiB LDS ring

typedef const __attribute__((address_space(1))) void gvoid;
typedef __attribute__((address_space(3))) void lvoid;

// ---------------- fp32 -> bf16 conversion (vectorized, grid-stride) ----------
__global__ void cvt_f32_bf16(const float* __restrict__ in, bf16_t* __restrict__ out,
                             long long n) {
  long long i = ((long long)blockIdx.x * blockDim.x + threadIdx.x) * 8;
  long long stride = (long long)gridDim.x * blockDim.x * 8;
  for (; i < n; i += stride) {
    float4 a = *(const float4*)(in + i);
    float4 b = *(const float4*)(in + i + 4);
    bf16x8 o;
    o[0] = (bf16_t)a.x; o[1] = (bf16_t)a.y; o[2] = (bf16_t)a.z; o[3] = (bf16_t)a.w;
    o[4] = (bf16_t)b.x; o[5] = (bf16_t)b.y; o[6] = (bf16_t)b.z; o[7] = (bf16_t)b.w;
    *(bf16x8*)(out + i) = o;
  }
}

// ---------------- deep-pipelined GEMM: C = A[M][K] * W[N][K]^T + bias --------
// 8 waves (2M x 4N), per-wave 128x64. 4-slot LDS ring, stage 3 ahead, counted
// vmcnt. Swizzle f(r)=(r>>1)&3 on 16B chunks (2-way residual = free).
// Intra-step pipeline: B-frag ping-pong + A-frag in-place re-read per row,
// so next-tile ds_reads drain under current-tile MFMAs.
__global__ __launch_bounds__(512, 2)
void gemm_deep(const bf16_t* __restrict__ A, const bf16_t* __restrict__ W,
               const float* __restrict__ bias, float* __restrict__ out) {
  __shared__ __align__(1024) char smem[NSLOT * SLOT_BYTES];  // 128 KiB

  const int nwg_n = N_DIM / BN;                 // 16
  const int nwg = (M_DIM / BM) * nwg_n;         // 2048 (divisible by 8)
  const int bid = blockIdx.x;
  const int swz = (bid & 7) * (nwg >> 3) + (bid >> 3);  // XCD-bijective
  const int bm0 = (swz / nwg_n) * BM;
  const int bn0 = (swz % nwg_n) * BN;

  const int tid = threadIdx.x;
  const int lane = tid & 63;
  const int wave = tid >> 6;
  const int wr = wave >> 2;   // 0..1 -> 128-row band
  const int wc = wave & 3;    // 0..3 -> 64-col band

  // ---- staging maps: linear LDS dest, inverse-swizzled global source ----
  // physical byte p in row holds logical col (p ^ f(row)), f(row)=((row>>1)&3)<<4
  const char* gA[2]; const char* gB[2]; int ldsA[2], ldsB[2];
#pragma unroll
  for (int s = 0; s < 2; ++s) {
    const int L = tid * 16 + s * 8192;
    const int row = L >> 6;
    const int c = (L & 63) ^ (((row >> 1) & 3) << 4);
    gA[s] = (const char*)A + (long long)(bm0 + row) * (K_DIM * 2) + c;
    gB[s] = (const char*)W + (long long)(bn0 + row) * (K_DIM * 2) + c;
    ldsA[s] = L;
    ldsB[s] = A_BYTES + L;
  }

  auto stage = [&](int t) {
    const int slot = (t & 3) * SLOT_BYTES;
    const long long ko = (long long)t * (BK * 2);
#pragma unroll
    for (int s = 0; s < 2; ++s)
      __builtin_amdgcn_global_load_lds((gvoid*)(gA[s] + ko),
                                       (lvoid*)(smem + slot + ldsA[s]), 16, 0, 0);
#pragma unroll
    for (int s = 0; s < 2; ++s)
      __builtin_amdgcn_global_load_lds((gvoid*)(gB[s] + ko),
                                       (lvoid*)(smem + slot + ldsB[s]), 16, 0, 0);
  };

  stage(0); stage(1); stage(2);  // 12 loads in flight

  // ---- fragment LDS byte offsets (swizzled), iteration-invariant ----
  int aoff[8], boff[4];
#pragma unroll
  for (int i = 0; i < 8; ++i) {
    const int r = wr * 128 + i * 16 + (lane & 15);
    aoff[i] = r * 64 + (((lane >> 4) << 4) ^ (((r >> 1) & 3) << 4));
  }
#pragma unroll
  for (int j = 0; j < 4; ++j) {
    const int r = wc * 64 + j * 16 + (lane & 15);
    boff[j] = A_BYTES + r * 64 + (((lane >> 4) << 4) ^ (((r >> 1) & 3) << 4));
  }

  f32x4 acc[8][4];
#pragma unroll
  for (int i = 0; i < 8; ++i)
#pragma unroll
    for (int j = 0; j < 4; ++j) acc[i][j] = (f32x4){0.f, 0.f, 0.f, 0.f};

  // ---- prologue: tile 0 into registers ----
  asm volatile("s_waitcnt vmcnt(8)" ::: "memory");   // tile 0 landed (own loads)
  __builtin_amdgcn_s_barrier();                      // all waves' loads landed
  __builtin_amdgcn_sched_barrier(0);

  bf16x8 af[8], bA[4], bB[4];
#pragma unroll
  for (int i = 0; i < 8; ++i) af[i] = *(const bf16x8*)(smem + aoff[i]);
#pragma unroll
  for (int j = 0; j < 4; ++j) bA[j] = *(const bf16x8*)(smem + boff[j]);
  asm volatile("s_waitcnt lgkmcnt(0)" ::: "memory");
  __builtin_amdgcn_sched_barrier(0);

  // ---- main loop: per step, reads of tile t+1 overlap MFMAs of tile t ----
  auto iter = [&](int t, bf16x8 (&bcur)[4], bf16x8 (&bnxt)[4]) {
    if (t + 3 < NT) stage(t + 3);
    const bool more = (t + 1 < NT);
    const char* bnext = smem + ((t + 1) & 3) * SLOT_BYTES;
    if (more) {
      // tile t+1 landed for every wave after [own counted vmcnt ; barrier]
      if (t + 3 < NT)      asm volatile("s_waitcnt vmcnt(8)" ::: "memory");
      else if (t + 2 < NT) asm volatile("s_waitcnt vmcnt(4)" ::: "memory");
      else                 asm volatile("s_waitcnt vmcnt(0)" ::: "memory");
      __builtin_amdgcn_s_barrier();
      __builtin_amdgcn_sched_barrier(0);
#pragma unroll
      for (int j = 0; j < 4; ++j) bnxt[j] = *(const bf16x8*)(bnext + boff[j]);
    }
    __builtin_amdgcn_s_setprio(1);
#pragma unroll
    for (int i = 0; i < 8; ++i) {
#pragma unroll
      for (int j = 0; j < 4; ++j)
        acc[i][j] = __builtin_amdgcn_mfma_f32_16x16x32_bf16(af[i], bcur[j], acc[i][j], 0, 0, 0);
      if (more) af[i] = *(const bf16x8*)(bnext + aoff[i]);  // WAR: after row i's MFMAs
    }
    __builtin_amdgcn_s_setprio(0);
    if (more) {
      // drain own frag reads before next barrier (slot-reuse safety)
      asm volatile("s_waitcnt lgkmcnt(0)" ::: "memory");
      __builtin_amdgcn_sched_barrier(0);
    }
  };

  for (int tt = 0; tt < NT; tt += 2) {  // NT even; static ping-pong (rule 20)
    iter(tt, bA, bB);
    iter(tt + 1, bB, bA);
  }

  // ---- epilogue: C/D layout col=lane&15, row=(lane>>4)*4+r (m89-verified) ----
#pragma unroll
  for (int j = 0; j < 4; ++j) {
    const int col = bn0 + wc * 64 + j * 16 + (lane & 15);
    const float bb = bias[col];
#pragma unroll
    for (int i = 0; i < 8; ++i) {
      const int row0 = bm0 + wr * 128 + i * 16 + (lane >> 4) * 4;
      f32x4 v = acc[i][j];
#pragma unroll
      for (int r = 0; r < 4; ++r)
        out[(long long)(row0 + r) * N_DIM + col] = v[r] + bb;
    }
  }
}

// ---------------- fallback (ws too small): fp32 reg-staged 128^2 ------------
__global__ __launch_bounds__(256, 2)
void gemm_small(const float* __restrict__ Ap, const float* __restrict__ Bp,
                const float* __restrict__ bias, float* __restrict__ out) {
  __shared__ bf16_t As[2][128 * 32];
  __shared__ bf16_t Bs[2][128 * 32];
  const int nwg_n = N_DIM / 128;
  const int nwg = (M_DIM / 128) * nwg_n;
  int bid = blockIdx.x;
  int swz = (bid & 7) * (nwg >> 3) + (bid >> 3);
  const int bm0 = (swz / nwg_n) * 128;
  const int bn0 = (swz % nwg_n) * 128;
  const int tid = threadIdx.x;
  const int lane = tid & 63;
  const int wave = tid >> 6;
  const int wr = wave >> 1, wc = wave & 1;
  const int arow = tid >> 2, ae = (tid & 3) * 8, ldsoff = tid * 8;
  f32x4 acc[4][4];
#pragma unroll
  for (int i = 0; i < 4; ++i)
#pragma unroll
    for (int j = 0; j < 4; ++j) acc[i][j] = (f32x4){0.f, 0.f, 0.f, 0.f};
  int aoff[4], boff[4];
#pragma unroll
  for (int i = 0; i < 4; ++i) {
    aoff[i] = (wr * 64 + i * 16 + (lane & 15)) * 32 + (lane >> 4) * 8;
    boff[i] = (wc * 64 + i * 16 + (lane & 15)) * 32 + (lane >> 4) * 8;
  }
  const float* gA = Ap + (long long)(bm0 + arow) * K_DIM + ae;
  const float* gB = Bp + (long long)(bn0 + arow) * K_DIM + ae;
  auto cvt8 = [](float4 a, float4 b) {
    bf16x8 o;
    o[0] = (bf16_t)a.x; o[1] = (bf16_t)a.y; o[2] = (bf16_t)a.z; o[3] = (bf16_t)a.w;
    o[4] = (bf16_t)b.x; o[5] = (bf16_t)b.y; o[6] = (bf16_t)b.z; o[7] = (bf16_t)b.w;
    return o;
  };
  {
    float4 a0 = *(const float4*)(gA), a1 = *(const float4*)(gA + 4);
    float4 a2 = *(const float4*)(gA + 64 * K_DIM), a3 = *(const float4*)(gA + 64 * K_DIM + 4);
    float4 b0 = *(const float4*)(gB), b1 = *(const float4*)(gB + 4);
    float4 b2 = *(const float4*)(gB + 64 * K_DIM), b3 = *(const float4*)(gB + 64 * K_DIM + 4);
    *(bf16x8*)&As[0][ldsoff] = cvt8(a0, a1);
    *(bf16x8*)&As[0][2048 + ldsoff] = cvt8(a2, a3);
    *(bf16x8*)&Bs[0][ldsoff] = cvt8(b0, b1);
    *(bf16x8*)&Bs[0][2048 + ldsoff] = cvt8(b2, b3);
  }
  __syncthreads();
  int buf = 0;
  for (int t = 0; t < K_DIM / 32; ++t) {
    float4 a0, a1, a2, a3, b0, b1, b2, b3;
    const bool pf = (t + 1 < K_DIM / 32);
    if (pf) {
      int kt = (t + 1) * 32;
      a0 = *(const float4*)(gA + kt); a1 = *(const float4*)(gA + kt + 4);
      a2 = *(const float4*)(gA + 64 * K_DIM + kt); a3 = *(const float4*)(gA + 64 * K_DIM + kt + 4);
      b0 = *(const float4*)(gB + kt); b1 = *(const float4*)(gB + kt + 4);
      b2 = *(const float4*)(gB + 64 * K_DIM + kt); b3 = *(const float4*)(gB + 64 * K_DIM + kt + 4);
    }
    bf16x8 af[4], bfr[4];
#pragma unroll
    for (int i = 0; i < 4; ++i) af[i] = *(const bf16x8*)&As[buf][aoff[i]];
#pragma unroll
    for (int j = 0; j < 4; ++j) bfr[j] = *(const bf16x8*)&Bs[buf][boff[j]];
#pragma unroll
    for (int i = 0; i < 4; ++i)
#pragma unroll
      for (int j = 0; j < 4; ++j)
        acc[i][j] = __builtin_amdgcn_mfma_f32_16x16x32_bf16(af[i], bfr[j], acc[i][j], 0, 0, 0);
    if (pf) {
      *(bf16x8*)&As[buf ^ 1][ldsoff] = cvt8(a0, a1);
      *(bf16x8*)&As[buf ^ 1][2048 + ldsoff] = cvt8(a2, a3);
      *(bf16x8*)&Bs[buf ^ 1][ldsoff] = cvt8(b0, b1);
      *(bf16x8*)&Bs[buf ^ 1][2048 + ldsoff] = cvt8(b2, b3);
    }
    __syncthreads();
    buf ^= 1;
  }
#pragma unroll
  for (int j = 0; j < 4; ++j) {
    const int col = bn0 + wc * 64 + j * 16 + (lane & 15);
    const float bb = bias[col];
#pragma unroll
    for (int i = 0; i < 4; ++i) {
      const int row0 = bm0 + wr * 64 + i * 16 + (lane >> 4) * 4;
      f32x4 v = acc[i][j];
#pragma unroll
      for (int r = 0; r < 4; ++r)
        out[(long long)(row0 + r) * N_DIM + col] = v[r] + bb;
    }
  }
}

extern "C" void kernel_launch(void* const* d_in, const int* in_sizes, int n_in,
                              void* d_out, int out_size, void* d_ws, size_t ws_size,
                              hipStream_t stream) {
  const float* x = (const float*)d_in[0];     // [8,4096,4096] fp32
  const float* w = (const float*)d_in[1];     // [4096,4096] fp32, {0,1,3}
  const float* bias = (const float*)d_in[2];  // [4096] fp32
  float* out = (float*)d_out;

  const size_t needA = (size_t)M_DIM * K_DIM * sizeof(bf16_t);  // 256 MiB
  const size_t needB = (size_t)N_DIM * K_DIM * sizeof(bf16_t);  // 32 MiB

  if (ws_size >= needA + needB) {
    bf16_t* Ab = (bf16_t*)d_ws;
    bf16_t* Wb = (bf16_t*)((char*)d_ws + needA);
    cvt_f32_bf16<<<2048, 256, 0, stream>>>(x, Ab, (long long)M_DIM * K_DIM);
    cvt_f32_bf16<<<1024, 256, 0, stream>>>(w, Wb, (long long)N_DIM * K_DIM);
    gemm_deep<<<(M_DIM / BM) * (N_DIM / BN), 512, 0, stream>>>(Ab, Wb, bias, out);
  } else {
    gemm_small<<<(M_DIM / 128) * (N_DIM / 128), 256, 0, stream>>>(x, w, bias, out);
  }
}

// Round 4
// 735.853 us; speedup vs baseline: 2.1915x; 1.5923x over previous
//
#include <hip/hip_runtime.h>
#include <stdint.h>

typedef __bf16 bf16_t;
typedef __bf16 bf16x8 __attribute__((ext_vector_type(8)));
typedef float  f32x4  __attribute__((ext_vector_type(4)));
typedef int    i32x4  __attribute__((ext_vector_type(4)));
typedef int    i32x16 __attribute__((ext_vector_type(16)));

#define M_DIM 32768
#define N_DIM 4096
#define K_DIM 4096

// i8 deep-pipeline GEMM geometry
#define BM 256
#define BN 256
#define BK 64                  // 64 i8 = 64 B per LDS row (same geometry as bf16 BK=32)
#define NT (K_DIM / BK)        // 64 K-steps
#define A_BYTES 16384          // 256 rows x 64 B
#define SLOT_BYTES 32768       // A half + B half
#define NSLOT 4                // 128 KiB LDS ring

typedef const __attribute__((address_space(1))) void gvoid;
typedef __attribute__((address_space(3))) void lvoid;

// ---------------- per-row quantize x: amax -> scale, rne to i8 ---------------
__device__ inline unsigned pack4(float4 v, float inv) {
  int a = (int)__builtin_rintf(v.x * inv);
  int b = (int)__builtin_rintf(v.y * inv);
  int c = (int)__builtin_rintf(v.z * inv);
  int d = (int)__builtin_rintf(v.w * inv);
  return (unsigned)((a & 255) | ((b & 255) << 8) | ((c & 255) << 16) | ((d & 255) << 24));
}

__global__ __launch_bounds__(256)
void quant_rows(const float* __restrict__ x, char* __restrict__ xq,
                float* __restrict__ scale) {
  const int row = blockIdx.x;
  const int t = threadIdx.x;
  const float* r = x + (long long)row * K_DIM;
  float4 v0 = ((const float4*)r)[t];
  float4 v1 = ((const float4*)r)[t + 256];
  float4 v2 = ((const float4*)r)[t + 512];
  float4 v3 = ((const float4*)r)[t + 768];
  float m = fabsf(v0.x);
  m = fmaxf(m, fabsf(v0.y)); m = fmaxf(m, fabsf(v0.z)); m = fmaxf(m, fabsf(v0.w));
  m = fmaxf(m, fabsf(v1.x)); m = fmaxf(m, fabsf(v1.y)); m = fmaxf(m, fabsf(v1.z)); m = fmaxf(m, fabsf(v1.w));
  m = fmaxf(m, fabsf(v2.x)); m = fmaxf(m, fabsf(v2.y)); m = fmaxf(m, fabsf(v2.z)); m = fmaxf(m, fabsf(v2.w));
  m = fmaxf(m, fabsf(v3.x)); m = fmaxf(m, fabsf(v3.y)); m = fmaxf(m, fabsf(v3.z)); m = fmaxf(m, fabsf(v3.w));
#pragma unroll
  for (int off = 32; off; off >>= 1) m = fmaxf(m, __shfl_xor(m, off));
  __shared__ float red[4];
  if ((t & 63) == 0) red[t >> 6] = m;
  __syncthreads();
  m = fmaxf(fmaxf(red[0], red[1]), fmaxf(red[2], red[3]));
  const float inv = m > 0.f ? 127.0f / m : 0.f;
  if (t == 0) scale[row] = m > 0.f ? m * (1.0f / 127.0f) : 0.f;
  unsigned* o = (unsigned*)(xq + (long long)row * K_DIM);
  o[t]       = pack4(v0, inv);
  o[t + 256] = pack4(v1, inv);
  o[t + 512] = pack4(v2, inv);
  o[t + 768] = pack4(v3, inv);
}

// ---------------- W -> i8 (values {0,1,3} exact) ----------------------------
__global__ void quant_w(const float* __restrict__ in, char* __restrict__ out,
                        long long n) {
  long long i = ((long long)blockIdx.x * blockDim.x + threadIdx.x) * 8;
  long long stride = (long long)gridDim.x * blockDim.x * 8;
  for (; i < n; i += stride) {
    float4 a = *(const float4*)(in + i);
    float4 b = *(const float4*)(in + i + 4);
    uint2 o;
    o.x = (unsigned)(((int)a.x & 255) | (((int)a.y & 255) << 8) |
                     (((int)a.z & 255) << 16) | (((int)a.w & 255) << 24));
    o.y = (unsigned)(((int)b.x & 255) | (((int)b.y & 255) << 8) |
                     (((int)b.z & 255) << 16) | (((int)b.w & 255) << 24));
    *(uint2*)(out + i) = o;
  }
}

// ---------------- i8 deep-pipelined GEMM: C = Xq * Wq^T, scaled + bias -------
// 8 waves (2M x 4N), per-wave 128x64 via 4x2 tiles of 32x32, K=32/MFMA.
// 4-slot LDS ring, stage 3 ahead, counted vmcnt. Swizzle f(r)=((r>>1)&3) on
// 16B chunks (verified conflict-free geometry). B ping-pong + A in-place
// re-read per row-tile so next-tile ds_reads drain under current MFMAs.
__global__ __launch_bounds__(512, 2)
void gemm_i8(const char* __restrict__ A, const char* __restrict__ W,
             const float* __restrict__ scale, const float* __restrict__ bias,
             float* __restrict__ out) {
  __shared__ __align__(1024) char smem[NSLOT * SLOT_BYTES];  // 128 KiB

  const int nwg_n = N_DIM / BN;                 // 16
  const int nwg = (M_DIM / BM) * nwg_n;         // 2048 (divisible by 8)
  const int bid = blockIdx.x;
  const int swz = (bid & 7) * (nwg >> 3) + (bid >> 3);  // XCD-bijective
  const int bm0 = (swz / nwg_n) * BM;
  const int bn0 = (swz % nwg_n) * BN;

  const int tid = threadIdx.x;
  const int lane = tid & 63;
  const int wave = tid >> 6;
  const int wr = wave >> 2;   // 0..1 -> 128-row band
  const int wc = wave & 3;    // 0..3 -> 64-col band

  // ---- staging maps: linear LDS dest, inverse-swizzled global source ----
  const char* gA[2]; const char* gB[2]; int ldsA[2], ldsB[2];
#pragma unroll
  for (int s = 0; s < 2; ++s) {
    const int L = tid * 16 + s * 8192;
    const int row = L >> 6;
    const int c = (L & 63) ^ (((row >> 1) & 3) << 4);
    gA[s] = A + (long long)(bm0 + row) * K_DIM + c;
    gB[s] = W + (long long)(bn0 + row) * K_DIM + c;
    ldsA[s] = L;
    ldsB[s] = A_BYTES + L;
  }

  auto stage = [&](int t) {
    const int slot = (t & 3) * SLOT_BYTES;
    const long long ko = (long long)t * BK;
#pragma unroll
    for (int s = 0; s < 2; ++s)
      __builtin_amdgcn_global_load_lds((gvoid*)(gA[s] + ko),
                                       (lvoid*)(smem + slot + ldsA[s]), 16, 0, 0);
#pragma unroll
    for (int s = 0; s < 2; ++s)
      __builtin_amdgcn_global_load_lds((gvoid*)(gB[s] + ko),
                                       (lvoid*)(smem + slot + ldsB[s]), 16, 0, 0);
  };

  stage(0); stage(1); stage(2);  // 12 loads in flight

  // ---- fragment LDS byte offsets (swizzled), iteration-invariant ----
  // A frag for 32x32x32 i8: lane holds row (lane&31), k = (lane>>5)*16 + [0..16)
  int aoff[4][2], boff[2][2];
#pragma unroll
  for (int i = 0; i < 4; ++i) {
    const int r = wr * 128 + i * 32 + (lane & 31);
#pragma unroll
    for (int ks = 0; ks < 2; ++ks) {
      const int ch = ((ks * 2 + (lane >> 5)) ^ ((r >> 1) & 3)) << 4;
      aoff[i][ks] = r * 64 + ch;
    }
  }
#pragma unroll
  for (int j = 0; j < 2; ++j) {
    const int r = wc * 64 + j * 32 + (lane & 31);
#pragma unroll
    for (int ks = 0; ks < 2; ++ks) {
      const int ch = ((ks * 2 + (lane >> 5)) ^ ((r >> 1) & 3)) << 4;
      boff[ks][j] = A_BYTES + r * 64 + ch;
    }
  }

  i32x16 acc[4][2];
#pragma unroll
  for (int i = 0; i < 4; ++i)
#pragma unroll
    for (int j = 0; j < 2; ++j) acc[i][j] = (i32x16){0};

  // ---- prologue: tile 0 fragments into registers ----
  asm volatile("s_waitcnt vmcnt(8)" ::: "memory");
  __builtin_amdgcn_s_barrier();
  __builtin_amdgcn_sched_barrier(0);

  i32x4 af[4][2], bA[2][2], bB[2][2];
#pragma unroll
  for (int i = 0; i < 4; ++i)
#pragma unroll
    for (int ks = 0; ks < 2; ++ks) af[i][ks] = *(const i32x4*)(smem + aoff[i][ks]);
#pragma unroll
  for (int ks = 0; ks < 2; ++ks)
#pragma unroll
    for (int j = 0; j < 2; ++j) bA[ks][j] = *(const i32x4*)(smem + boff[ks][j]);
  asm volatile("s_waitcnt lgkmcnt(0)" ::: "memory");
  __builtin_amdgcn_sched_barrier(0);

  // ---- main loop: reads of tile t+1 overlap MFMAs of tile t ----
  auto iter = [&](int t, i32x4 (&bcur)[2][2], i32x4 (&bnxt)[2][2]) {
    if (t + 3 < NT) stage(t + 3);
    const bool more = (t + 1 < NT);
    const char* bnext = smem + ((t + 1) & 3) * SLOT_BYTES;
    if (more) {
      if (t + 3 < NT)      asm volatile("s_waitcnt vmcnt(8)" ::: "memory");
      else if (t + 2 < NT) asm volatile("s_waitcnt vmcnt(4)" ::: "memory");
      else                 asm volatile("s_waitcnt vmcnt(0)" ::: "memory");
      __builtin_amdgcn_s_barrier();
      __builtin_amdgcn_sched_barrier(0);
#pragma unroll
      for (int ks = 0; ks < 2; ++ks)
#pragma unroll
        for (int j = 0; j < 2; ++j) bnxt[ks][j] = *(const i32x4*)(bnext + boff[ks][j]);
    }
    __builtin_amdgcn_s_setprio(1);
#pragma unroll
    for (int i = 0; i < 4; ++i) {
#pragma unroll
      for (int ks = 0; ks < 2; ++ks)
#pragma unroll
        for (int j = 0; j < 2; ++j)
          acc[i][j] = __builtin_amdgcn_mfma_i32_32x32x32_i8(af[i][ks], bcur[ks][j],
                                                            acc[i][j], 0, 0, 0);
      if (more) {  // WAR-safe: af[i] dead after its 4 MFMAs
        af[i][0] = *(const i32x4*)(bnext + aoff[i][0]);
        af[i][1] = *(const i32x4*)(bnext + aoff[i][1]);
      }
    }
    __builtin_amdgcn_s_setprio(0);
    if (more) {
      asm volatile("s_waitcnt lgkmcnt(0)" ::: "memory");  // slot-reuse safety
      __builtin_amdgcn_sched_barrier(0);
    }
  };

  for (int tt = 0; tt < NT; tt += 2) {  // NT even; static ping-pong
    iter(tt, bA, bB);
    iter(tt + 1, bB, bA);
  }

  // ---- epilogue: stage scales+bias in LDS, then scaled store ----
  __syncthreads();
  float* fs = (float*)smem;
  if (tid < 256) {
    fs[tid] = scale[bm0 + tid];
    fs[256 + tid] = bias[bn0 + tid];
  }
  __syncthreads();

  // C/D 32x32 layout: col=lane&31, row=(reg&3)+8*(reg>>2)+4*(lane>>5)
#pragma unroll
  for (int i = 0; i < 4; ++i) {
#pragma unroll
    for (int j = 0; j < 2; ++j) {
      const int colb = wc * 64 + j * 32 + (lane & 31);
      const float bb = fs[256 + colb];
      const long long col = bn0 + colb;
#pragma unroll
      for (int e = 0; e < 16; ++e) {
        const int rowl = wr * 128 + i * 32 + 4 * (lane >> 5) + (e & 3) + 8 * (e >> 2);
        out[(long long)(bm0 + rowl) * N_DIM + col] =
            (float)acc[i][j][e] * fs[rowl] + bb;
      }
    }
  }
}

// ---------------- fallback (ws too small): fp32 reg-staged 128^2 bf16 -------
__global__ __launch_bounds__(256, 2)
void gemm_small(const float* __restrict__ Ap, const float* __restrict__ Bp,
                const float* __restrict__ bias, float* __restrict__ out) {
  __shared__ bf16_t As[2][128 * 32];
  __shared__ bf16_t Bs[2][128 * 32];
  const int nwg_n = N_DIM / 128;
  const int nwg = (M_DIM / 128) * nwg_n;
  int bid = blockIdx.x;
  int swz = (bid & 7) * (nwg >> 3) + (bid >> 3);
  const int bm0 = (swz / nwg_n) * 128;
  const int bn0 = (swz % nwg_n) * 128;
  const int tid = threadIdx.x;
  const int lane = tid & 63;
  const int wave = tid >> 6;
  const int wr = wave >> 1, wc = wave & 1;
  const int arow = tid >> 2, ae = (tid & 3) * 8, ldsoff = tid * 8;
  f32x4 acc[4][4];
#pragma unroll
  for (int i = 0; i < 4; ++i)
#pragma unroll
    for (int j = 0; j < 4; ++j) acc[i][j] = (f32x4){0.f, 0.f, 0.f, 0.f};
  int aoff[4], boff[4];
#pragma unroll
  for (int i = 0; i < 4; ++i) {
    aoff[i] = (wr * 64 + i * 16 + (lane & 15)) * 32 + (lane >> 4) * 8;
    boff[i] = (wc * 64 + i * 16 + (lane & 15)) * 32 + (lane >> 4) * 8;
  }
  const float* gA = Ap + (long long)(bm0 + arow) * K_DIM + ae;
  const float* gB = Bp + (long long)(bn0 + arow) * K_DIM + ae;
  auto cvt8 = [](float4 a, float4 b) {
    bf16x8 o;
    o[0] = (bf16_t)a.x; o[1] = (bf16_t)a.y; o[2] = (bf16_t)a.z; o[3] = (bf16_t)a.w;
    o[4] = (bf16_t)b.x; o[5] = (bf16_t)b.y; o[6] = (bf16_t)b.z; o[7] = (bf16_t)b.w;
    return o;
  };
  {
    float4 a0 = *(const float4*)(gA), a1 = *(const float4*)(gA + 4);
    float4 a2 = *(const float4*)(gA + 64 * K_DIM), a3 = *(const float4*)(gA + 64 * K_DIM + 4);
    float4 b0 = *(const float4*)(gB), b1 = *(const float4*)(gB + 4);
    float4 b2 = *(const float4*)(gB + 64 * K_DIM), b3 = *(const float4*)(gB + 64 * K_DIM + 4);
    *(bf16x8*)&As[0][ldsoff] = cvt8(a0, a1);
    *(bf16x8*)&As[0][2048 + ldsoff] = cvt8(a2, a3);
    *(bf16x8*)&Bs[0][ldsoff] = cvt8(b0, b1);
    *(bf16x8*)&Bs[0][2048 + ldsoff] = cvt8(b2, b3);
  }
  __syncthreads();
  int buf = 0;
  for (int t = 0; t < K_DIM / 32; ++t) {
    float4 a0, a1, a2, a3, b0, b1, b2, b3;
    const bool pf = (t + 1 < K_DIM / 32);
    if (pf) {
      int kt = (t + 1) * 32;
      a0 = *(const float4*)(gA + kt); a1 = *(const float4*)(gA + kt + 4);
      a2 = *(const float4*)(gA + 64 * K_DIM + kt); a3 = *(const float4*)(gA + 64 * K_DIM + kt + 4);
      b0 = *(const float4*)(gB + kt); b1 = *(const float4*)(gB + kt + 4);
      b2 = *(const float4*)(gB + 64 * K_DIM + kt); b3 = *(const float4*)(gB + 64 * K_DIM + kt + 4);
    }
    bf16x8 af[4], bfr[4];
#pragma unroll
    for (int i = 0; i < 4; ++i) af[i] = *(const bf16x8*)&As[buf][aoff[i]];
#pragma unroll
    for (int j = 0; j < 4; ++j) bfr[j] = *(const bf16x8*)&Bs[buf][boff[j]];
#pragma unroll
    for (int i = 0; i < 4; ++i)
#pragma unroll
      for (int j = 0; j < 4; ++j)
        acc[i][j] = __builtin_amdgcn_mfma_f32_16x16x32_bf16(af[i], bfr[j], acc[i][j], 0, 0, 0);
    if (pf) {
      *(bf16x8*)&As[buf ^ 1][ldsoff] = cvt8(a0, a1);
      *(bf16x8*)&As[buf ^ 1][2048 + ldsoff] = cvt8(a2, a3);
      *(bf16x8*)&Bs[buf ^ 1][ldsoff] = cvt8(b0, b1);
      *(bf16x8*)&Bs[buf ^ 1][2048 + ldsoff] = cvt8(b2, b3);
    }
    __syncthreads();
    buf ^= 1;
  }
#pragma unroll
  for (int j = 0; j < 4; ++j) {
    const int col = bn0 + wc * 64 + j * 16 + (lane & 15);
    const float bb = bias[col];
#pragma unroll
    for (int i = 0; i < 4; ++i) {
      const int row0 = bm0 + wr * 64 + i * 16 + (lane >> 4) * 4;
      f32x4 v = acc[i][j];
#pragma unroll
      for (int r = 0; r < 4; ++r)
        out[(long long)(row0 + r) * N_DIM + col] = v[r] + bb;
    }
  }
}

extern "C" void kernel_launch(void* const* d_in, const int* in_sizes, int n_in,
                              void* d_out, int out_size, void* d_ws, size_t ws_size,
                              hipStream_t stream) {
  const float* x = (const float*)d_in[0];     // [8,4096,4096] fp32
  const float* w = (const float*)d_in[1];     // [4096,4096] fp32, {0,1,3}
  const float* bias = (const float*)d_in[2];  // [4096] fp32
  float* out = (float*)d_out;

  const size_t offW = (size_t)M_DIM * K_DIM;              // 128 MiB
  const size_t offS = offW + (size_t)N_DIM * K_DIM;       // +16 MiB
  const size_t need = offS + (size_t)M_DIM * sizeof(float);

  if (ws_size >= need) {
    char* xq = (char*)d_ws;
    char* wq = (char*)d_ws + offW;
    float* sc = (float*)((char*)d_ws + offS);
    quant_rows<<<M_DIM, 256, 0, stream>>>(x, xq, sc);
    quant_w<<<1024, 256, 0, stream>>>(w, wq, (long long)N_DIM * K_DIM);
    gemm_i8<<<(M_DIM / BM) * (N_DIM / BN), 512, 0, stream>>>(xq, wq, sc, bias, out);
  } else {
    gemm_small<<<(M_DIM / 128) * (N_DIM / 128), 256, 0, stream>>>(x, w, bias, out);
  }
}

// Round 5
// 710.368 us; speedup vs baseline: 2.2702x; 1.0359x over previous
//
#include <hip/hip_runtime.h>
#include <stdint.h>

typedef __bf16 bf16_t;
typedef __bf16 bf16x8 __attribute__((ext_vector_type(8)));
typedef float  f32x4  __attribute__((ext_vector_type(4)));
typedef int    i32x4  __attribute__((ext_vector_type(4)));
typedef int    i32x16 __attribute__((ext_vector_type(16)));

#define M_DIM 32768
#define N_DIM 4096
#define K_DIM 4096

// i8 deep-pipeline GEMM geometry
#define BM 256
#define BN 256
#define BK 64                  // 64 i8 = 64 B per LDS row
#define NT (K_DIM / BK)        // 64 K-steps
#define A_BYTES 16384          // 256 rows x 64 B
#define B_BASE  (A_BYTES + 64) // 64 B pad: decorrelate A/B bank phase
#define SLOT_STRIDE (B_BASE + A_BYTES)  // 32832
#define NSLOT 4                // ring of 4 slots (~128 KiB)

typedef const __attribute__((address_space(1))) void gvoid;
typedef __attribute__((address_space(3))) void lvoid;

// ---------------- per-row quantize x: amax -> scale, rne to i8 ---------------
__device__ inline unsigned pack4(float4 v, float inv) {
  int a = (int)__builtin_rintf(v.x * inv);
  int b = (int)__builtin_rintf(v.y * inv);
  int c = (int)__builtin_rintf(v.z * inv);
  int d = (int)__builtin_rintf(v.w * inv);
  return (unsigned)((a & 255) | ((b & 255) << 8) | ((c & 255) << 16) | ((d & 255) << 24));
}

__global__ __launch_bounds__(256)
void quant_rows(const float* __restrict__ x, char* __restrict__ xq,
                float* __restrict__ scale) {
  const int row = blockIdx.x;
  const int t = threadIdx.x;
  const float* r = x + (long long)row * K_DIM;
  float4 v0 = ((const float4*)r)[t];
  float4 v1 = ((const float4*)r)[t + 256];
  float4 v2 = ((const float4*)r)[t + 512];
  float4 v3 = ((const float4*)r)[t + 768];
  float m = fabsf(v0.x);
  m = fmaxf(m, fabsf(v0.y)); m = fmaxf(m, fabsf(v0.z)); m = fmaxf(m, fabsf(v0.w));
  m = fmaxf(m, fabsf(v1.x)); m = fmaxf(m, fabsf(v1.y)); m = fmaxf(m, fabsf(v1.z)); m = fmaxf(m, fabsf(v1.w));
  m = fmaxf(m, fabsf(v2.x)); m = fmaxf(m, fabsf(v2.y)); m = fmaxf(m, fabsf(v2.z)); m = fmaxf(m, fabsf(v2.w));
  m = fmaxf(m, fabsf(v3.x)); m = fmaxf(m, fabsf(v3.y)); m = fmaxf(m, fabsf(v3.z)); m = fmaxf(m, fabsf(v3.w));
#pragma unroll
  for (int off = 32; off; off >>= 1) m = fmaxf(m, __shfl_xor(m, off));
  __shared__ float red[4];
  if ((t & 63) == 0) red[t >> 6] = m;
  __syncthreads();
  m = fmaxf(fmaxf(red[0], red[1]), fmaxf(red[2], red[3]));
  const float inv = m > 0.f ? 127.0f / m : 0.f;
  if (t == 0) scale[row] = m > 0.f ? m * (1.0f / 127.0f) : 0.f;
  unsigned* o = (unsigned*)(xq + (long long)row * K_DIM);
  o[t]       = pack4(v0, inv);
  o[t + 256] = pack4(v1, inv);
  o[t + 512] = pack4(v2, inv);
  o[t + 768] = pack4(v3, inv);
}

// ---------------- W -> i8 (values {0,1,3} exact) ----------------------------
__global__ void quant_w(const float* __restrict__ in, char* __restrict__ out,
                        long long n) {
  long long i = ((long long)blockIdx.x * blockDim.x + threadIdx.x) * 8;
  long long stride = (long long)gridDim.x * blockDim.x * 8;
  for (; i < n; i += stride) {
    float4 a = *(const float4*)(in + i);
    float4 b = *(const float4*)(in + i + 4);
    uint2 o;
    o.x = (unsigned)(((int)a.x & 255) | (((int)a.y & 255) << 8) |
                     (((int)a.z & 255) << 16) | (((int)a.w & 255) << 24));
    o.y = (unsigned)(((int)b.x & 255) | (((int)b.y & 255) << 8) |
                     (((int)b.z & 255) << 16) | (((int)b.w & 255) << 24));
    *(uint2*)(out + i) = o;
  }
}

// ---------------- i8 deep-pipelined GEMM: C = Xq * Wq^T, scaled + bias -------
// 8 waves (2M x 4N), per-wave 128x64 via 4x2 tiles of 32x32x32.
// Ring-4 LDS, stage TWO ahead, counted vmcnt(4), NO per-step lgkm drain:
// slot (t+2)&3 == slot (t-2)&3, whose reads were consumed (auto-lgkm before
// their burst) two barriers ago -> restage is race-free without a drain.
// Frag reads in flight ride across the barrier and drain under next burst.
__global__ __launch_bounds__(512, 2)
void gemm_i8(const char* __restrict__ A, const char* __restrict__ W,
             const float* __restrict__ scale, const float* __restrict__ bias,
             float* __restrict__ out) {
  __shared__ __align__(1024) char smem[NSLOT * SLOT_STRIDE];

  const int nwg_n = N_DIM / BN;                 // 16
  const int nwg = (M_DIM / BM) * nwg_n;         // 2048 (divisible by 8)
  const int bid = blockIdx.x;
  const int swz = (bid & 7) * (nwg >> 3) + (bid >> 3);  // XCD-bijective
  const int bm0 = (swz / nwg_n) * BM;
  const int bn0 = (swz % nwg_n) * BN;

  const int tid = threadIdx.x;
  const int lane = tid & 63;
  const int wave = tid >> 6;
  const int wr = wave >> 2;   // 0..1 -> 128-row band
  const int wc = wave & 3;    // 0..3 -> 64-col band

  // ---- staging maps: linear LDS dest, inverse-swizzled global source ----
  const char* gA[2]; const char* gB[2]; int ldsA[2], ldsB[2];
#pragma unroll
  for (int s = 0; s < 2; ++s) {
    const int L = tid * 16 + s * 8192;
    const int row = L >> 6;
    const int c = (L & 63) ^ (((row >> 1) & 3) << 4);
    gA[s] = A + (long long)(bm0 + row) * K_DIM + c;
    gB[s] = W + (long long)(bn0 + row) * K_DIM + c;
    ldsA[s] = L;
    ldsB[s] = B_BASE + L;
  }

  auto stage = [&](int t) {
    const int slot = (t & 3) * SLOT_STRIDE;
    const long long ko = (long long)t * BK;
#pragma unroll
    for (int s = 0; s < 2; ++s)
      __builtin_amdgcn_global_load_lds((gvoid*)(gA[s] + ko),
                                       (lvoid*)(smem + slot + ldsA[s]), 16, 0, 0);
#pragma unroll
    for (int s = 0; s < 2; ++s)
      __builtin_amdgcn_global_load_lds((gvoid*)(gB[s] + ko),
                                       (lvoid*)(smem + slot + ldsB[s]), 16, 0, 0);
  };

  stage(0); stage(1);  // 8 loads in flight (2-deep)

  // ---- fragment LDS byte offsets (swizzled), iteration-invariant ----
  // A frag for 32x32x32 i8: lane holds row (lane&31), k = (lane>>5)*16 + [0..16)
  int aoff[4][2], boff[2][2];
#pragma unroll
  for (int i = 0; i < 4; ++i) {
    const int r = wr * 128 + i * 32 + (lane & 31);
#pragma unroll
    for (int ks = 0; ks < 2; ++ks) {
      const int ch = ((ks * 2 + (lane >> 5)) ^ ((r >> 1) & 3)) << 4;
      aoff[i][ks] = r * 64 + ch;
    }
  }
#pragma unroll
  for (int j = 0; j < 2; ++j) {
    const int r = wc * 64 + j * 32 + (lane & 31);
#pragma unroll
    for (int ks = 0; ks < 2; ++ks) {
      const int ch = ((ks * 2 + (lane >> 5)) ^ ((r >> 1) & 3)) << 4;
      boff[ks][j] = B_BASE + r * 64 + ch;
    }
  }

  i32x16 acc[4][2];
#pragma unroll
  for (int i = 0; i < 4; ++i)
#pragma unroll
    for (int j = 0; j < 2; ++j) acc[i][j] = (i32x16){0};

  // ---- prologue: tile 0 fragments into registers ----
  asm volatile("s_waitcnt vmcnt(4)" ::: "memory");  // tile 0 landed
  __builtin_amdgcn_s_barrier();
  __builtin_amdgcn_sched_barrier(0);

  i32x4 af[4][2], bA[2][2], bB[2][2];
#pragma unroll
  for (int i = 0; i < 4; ++i)
#pragma unroll
    for (int ks = 0; ks < 2; ++ks) af[i][ks] = *(const i32x4*)(smem + aoff[i][ks]);
#pragma unroll
  for (int ks = 0; ks < 2; ++ks)
#pragma unroll
    for (int j = 0; j < 2; ++j) bA[ks][j] = *(const i32x4*)(smem + boff[ks][j]);
  // no explicit lgkm: compiler auto-waits before first consuming MFMA

  // ---- main loop ----
  auto iter = [&](int t, i32x4 (&bcur)[2][2], i32x4 (&bnxt)[2][2]) {
    if (t + 2 < NT) stage(t + 2);
    const bool more = (t + 1 < NT);
    const char* bnext = smem + ((t + 1) & 3) * SLOT_STRIDE;
    if (more) {
      // gate: tile t+1 landed for all waves. outstanding: {t+1?, t+2} <= 8
      if (t + 2 < NT) asm volatile("s_waitcnt vmcnt(4)" ::: "memory");
      else            asm volatile("s_waitcnt vmcnt(0)" ::: "memory");
      __builtin_amdgcn_sched_barrier(0);
      __builtin_amdgcn_s_barrier();
      __builtin_amdgcn_sched_barrier(0);
#pragma unroll
      for (int ks = 0; ks < 2; ++ks)
#pragma unroll
        for (int j = 0; j < 2; ++j) bnxt[ks][j] = *(const i32x4*)(bnext + boff[ks][j]);
    }
    __builtin_amdgcn_s_setprio(1);
#pragma unroll
    for (int i = 0; i < 4; ++i) {
#pragma unroll
      for (int ks = 0; ks < 2; ++ks)
#pragma unroll
        for (int j = 0; j < 2; ++j)
          acc[i][j] = __builtin_amdgcn_mfma_i32_32x32x32_i8(af[i][ks], bcur[ks][j],
                                                            acc[i][j], 0, 0, 0);
      if (more) {  // WAR-safe: af[i] dead after its 4 MFMAs; drains under burst t+1
        af[i][0] = *(const i32x4*)(bnext + aoff[i][0]);
        af[i][1] = *(const i32x4*)(bnext + aoff[i][1]);
      }
    }
    __builtin_amdgcn_s_setprio(0);
  };

  for (int tt = 0; tt < NT; tt += 2) {  // NT even; static ping-pong
    iter(tt, bA, bB);
    iter(tt + 1, bB, bA);
  }

  // ---- epilogue: stage scales+bias in LDS, then scaled store ----
  __syncthreads();
  float* fs = (float*)smem;
  if (tid < 256) {
    fs[tid] = scale[bm0 + tid];
    fs[256 + tid] = bias[bn0 + tid];
  }
  __syncthreads();

  // C/D 32x32 layout: col=lane&31, row=(reg&3)+8*(reg>>2)+4*(lane>>5)
#pragma unroll
  for (int i = 0; i < 4; ++i) {
#pragma unroll
    for (int j = 0; j < 2; ++j) {
      const int colb = wc * 64 + j * 32 + (lane & 31);
      const float bb = fs[256 + colb];
      const long long col = bn0 + colb;
#pragma unroll
      for (int e = 0; e < 16; ++e) {
        const int rowl = wr * 128 + i * 32 + 4 * (lane >> 5) + (e & 3) + 8 * (e >> 2);
        out[(long long)(bm0 + rowl) * N_DIM + col] =
            (float)acc[i][j][e] * fs[rowl] + bb;
      }
    }
  }
}

// ---------------- fallback (ws too small): fp32 reg-staged 128^2 bf16 -------
__global__ __launch_bounds__(256, 2)
void gemm_small(const float* __restrict__ Ap, const float* __restrict__ Bp,
                const float* __restrict__ bias, float* __restrict__ out) {
  __shared__ bf16_t As[2][128 * 32];
  __shared__ bf16_t Bs[2][128 * 32];
  const int nwg_n = N_DIM / 128;
  const int nwg = (M_DIM / 128) * nwg_n;
  int bid = blockIdx.x;
  int swz = (bid & 7) * (nwg >> 3) + (bid >> 3);
  const int bm0 = (swz / nwg_n) * 128;
  const int bn0 = (swz % nwg_n) * 128;
  const int tid = threadIdx.x;
  const int lane = tid & 63;
  const int wave = tid >> 6;
  const int wr = wave >> 1, wc = wave & 1;
  const int arow = tid >> 2, ae = (tid & 3) * 8, ldsoff = tid * 8;
  f32x4 acc[4][4];
#pragma unroll
  for (int i = 0; i < 4; ++i)
#pragma unroll
    for (int j = 0; j < 4; ++j) acc[i][j] = (f32x4){0.f, 0.f, 0.f, 0.f};
  int aoff[4], boff[4];
#pragma unroll
  for (int i = 0; i < 4; ++i) {
    aoff[i] = (wr * 64 + i * 16 + (lane & 15)) * 32 + (lane >> 4) * 8;
    boff[i] = (wc * 64 + i * 16 + (lane & 15)) * 32 + (lane >> 4) * 8;
  }
  const float* gA = Ap + (long long)(bm0 + arow) * K_DIM + ae;
  const float* gB = Bp + (long long)(bn0 + arow) * K_DIM + ae;
  auto cvt8 = [](float4 a, float4 b) {
    bf16x8 o;
    o[0] = (bf16_t)a.x; o[1] = (bf16_t)a.y; o[2] = (bf16_t)a.z; o[3] = (bf16_t)a.w;
    o[4] = (bf16_t)b.x; o[5] = (bf16_t)b.y; o[6] = (bf16_t)b.z; o[7] = (bf16_t)b.w;
    return o;
  };
  {
    float4 a0 = *(const float4*)(gA), a1 = *(const float4*)(gA + 4);
    float4 a2 = *(const float4*)(gA + 64 * K_DIM), a3 = *(const float4*)(gA + 64 * K_DIM + 4);
    float4 b0 = *(const float4*)(gB), b1 = *(const float4*)(gB + 4);
    float4 b2 = *(const float4*)(gB + 64 * K_DIM), b3 = *(const float4*)(gB + 64 * K_DIM + 4);
    *(bf16x8*)&As[0][ldsoff] = cvt8(a0, a1);
    *(bf16x8*)&As[0][2048 + ldsoff] = cvt8(a2, a3);
    *(bf16x8*)&Bs[0][ldsoff] = cvt8(b0, b1);
    *(bf16x8*)&Bs[0][2048 + ldsoff] = cvt8(b2, b3);
  }
  __syncthreads();
  int buf = 0;
  for (int t = 0; t < K_DIM / 32; ++t) {
    float4 a0, a1, a2, a3, b0, b1, b2, b3;
    const bool pf = (t + 1 < K_DIM / 32);
    if (pf) {
      int kt = (t + 1) * 32;
      a0 = *(const float4*)(gA + kt); a1 = *(const float4*)(gA + kt + 4);
      a2 = *(const float4*)(gA + 64 * K_DIM + kt); a3 = *(const float4*)(gA + 64 * K_DIM + kt + 4);
      b0 = *(const float4*)(gB + kt); b1 = *(const float4*)(gB + kt + 4);
      b2 = *(const float4*)(gB + 64 * K_DIM + kt); b3 = *(const float4*)(gB + 64 * K_DIM + kt + 4);
    }
    bf16x8 af[4], bfr[4];
#pragma unroll
    for (int i = 0; i < 4; ++i) af[i] = *(const bf16x8*)&As[buf][aoff[i]];
#pragma unroll
    for (int j = 0; j < 4; ++j) bfr[j] = *(const bf16x8*)&Bs[buf][boff[j]];
#pragma unroll
    for (int i = 0; i < 4; ++i)
#pragma unroll
      for (int j = 0; j < 4; ++j)
        acc[i][j] = __builtin_amdgcn_mfma_f32_16x16x32_bf16(af[i], bfr[j], acc[i][j], 0, 0, 0);
    if (pf) {
      *(bf16x8*)&As[buf ^ 1][ldsoff] = cvt8(a0, a1);
      *(bf16x8*)&As[buf ^ 1][2048 + ldsoff] = cvt8(a2, a3);
      *(bf16x8*)&Bs[buf ^ 1][ldsoff] = cvt8(b0, b1);
      *(bf16x8*)&Bs[buf ^ 1][2048 + ldsoff] = cvt8(b2, b3);
    }
    __syncthreads();
    buf ^= 1;
  }
#pragma unroll
  for (int j = 0; j < 4; ++j) {
    const int col = bn0 + wc * 64 + j * 16 + (lane & 15);
    const float bb = bias[col];
#pragma unroll
    for (int i = 0; i < 4; ++i) {
      const int row0 = bm0 + wr * 64 + i * 16 + (lane >> 4) * 4;
      f32x4 v = acc[i][j];
#pragma unroll
      for (int r = 0; r < 4; ++r)
        out[(long long)(row0 + r) * N_DIM + col] = v[r] + bb;
    }
  }
}

extern "C" void kernel_launch(void* const* d_in, const int* in_sizes, int n_in,
                              void* d_out, int out_size, void* d_ws, size_t ws_size,
                              hipStream_t stream) {
  const float* x = (const float*)d_in[0];     // [8,4096,4096] fp32
  const float* w = (const float*)d_in[1];     // [4096,4096] fp32, {0,1,3}
  const float* bias = (const float*)d_in[2];  // [4096] fp32
  float* out = (float*)d_out;

  const size_t offW = (size_t)M_DIM * K_DIM;              // 128 MiB
  const size_t offS = offW + (size_t)N_DIM * K_DIM;       // +16 MiB
  const size_t need = offS + (size_t)M_DIM * sizeof(float);

  if (ws_size >= need) {
    char* xq = (char*)d_ws;
    char* wq = (char*)d_ws + offW;
    float* sc = (float*)((char*)d_ws + offS);
    quant_rows<<<M_DIM, 256, 0, stream>>>(x, xq, sc);
    quant_w<<<1024, 256, 0, stream>>>(w, wq, (long long)N_DIM * K_DIM);
    gemm_i8<<<(M_DIM / BM) * (N_DIM / BN), 512, 0, stream>>>(xq, wq, sc, bias, out);
  } else {
    gemm_small<<<(M_DIM / 128) * (N_DIM / 128), 256, 0, stream>>>(x, w, bias, out);
  }
}